// Round 2
// baseline (1034.809 us; speedup 1.0000x reference)
//
#include <hip/hip_runtime.h>

#define BATCH 16
#define CIN   512
#define COUT  512
#define HDIM  64
#define HW    4096
#define STY   512
#define NTAP  9
// 1/sqrt(512*9)
#define SCALE 0.014731391274719739f

typedef __bf16 bf16x8 __attribute__((ext_vector_type(8)));
typedef float  f32x4  __attribute__((ext_vector_type(4)));

static __device__ __forceinline__ unsigned short f2bf(float f) {
  union { float f; unsigned u; } v; v.f = f;
  unsigned u = v.u;
  u += 0x7fffu + ((u >> 16) & 1u);   // RNE; inputs finite
  return (unsigned short)(u >> 16);
}
static __device__ __forceinline__ float bf2f(unsigned short h) {
  union { unsigned u; float f; } v; v.u = ((unsigned)h) << 16;
  return v.f;
}

// S[b][ci] = SCALE * (sum_j style[b][j]*mod_w[ci][j] + mod_b[ci]); 64 blocks
__global__ void k_style(const float* __restrict__ style, const float* __restrict__ mod_w,
                        const float* __restrict__ mod_b, float* __restrict__ S) {
  __shared__ __align__(16) float sty[STY];
  int b = blockIdx.x;
  for (int j = threadIdx.x; j < STY; j += 128) sty[j] = style[b*STY + j];
  __syncthreads();
  int ci = blockIdx.y * 128 + threadIdx.x;
  const float4* wr = reinterpret_cast<const float4*>(mod_w + ci*STY);
  const float4* sr = reinterpret_cast<const float4*>(sty);
  float acc = 0.f;
  #pragma unroll 4
  for (int j = 0; j < STY/4; ++j) {
    float4 w = wr[j], s = sr[j];
    acc += w.x*s.x + w.y*s.y + w.z*s.z + w.w*s.w;
  }
  S[b*CIN + ci] = SCALE * (acc + mod_b[ci]);
}

// wsq[co][ci] = sum_tap weight^2 ; wpack[tap][co][ci] = bf16(weight)
// LDS-staged for coalesced global reads.
__global__ void k_wsq_pack(const float* __restrict__ weight, float* __restrict__ wsq,
                           unsigned short* __restrict__ wpack) {
  __shared__ __align__(16) float w[CIN*NTAP];
  int co = blockIdx.x;
  for (int i = threadIdx.x; i < CIN*NTAP; i += 256)
    w[i] = weight[co*(CIN*NTAP) + i];
  __syncthreads();
  for (int ci = threadIdx.x; ci < CIN; ci += 256) {
    float ssq = 0.f;
    #pragma unroll
    for (int t = 0; t < NTAP; ++t) {
      float v = w[ci*NTAP + t];
      ssq += v * v;
      wpack[(t*COUT + co)*CIN + ci] = f2bf(v);
    }
    wsq[co*CIN + ci] = ssq;
  }
}

// D[b][co] = rsqrt(sum_ci S^2 * wsq + eps); one wave per (b,co)
__global__ void k_demod(const float* __restrict__ S, const float* __restrict__ wsq,
                        float* __restrict__ D) {
  int wid  = blockIdx.x * 4 + (threadIdx.x >> 6);  // b*512 + co
  int lane = threadIdx.x & 63;
  int b  = wid >> 9;
  int co = wid & 511;
  float sum = 0.f;
  #pragma unroll
  for (int i = 0; i < CIN/64; ++i) {
    int ci = lane + i*64;
    float s = S[b*CIN + ci];
    sum += s * s * wsq[co*CIN + ci];
  }
  #pragma unroll
  for (int off = 32; off > 0; off >>= 1) sum += __shfl_down(sum, off);
  if (lane == 0) D[b*COUT + co] = rsqrtf(sum + 1e-8f);
}

// wmodK[b][c0][tg][co][96] : GEMM-K-ordered modulated bf16 weights.
// K within (c0,tg) section: k96 = tloc*32 + g*8 + j -> tap = tg*3+tloc, ci = c0*32+g*8+j
__global__ void k_wmod(const unsigned short* __restrict__ wpack, const float* __restrict__ S,
                       const float* __restrict__ D, unsigned short* __restrict__ wmodK) {
  int g = blockIdx.x * 256 + threadIdx.x;     // uint4 id; 16*16*3*512*12 total
  int q    = g % 12;
  int t1   = g / 12;
  int co   = t1 & 511;
  int t2   = t1 >> 9;
  int tg   = t2 % 3;
  int t3   = t2 / 3;
  int c0   = t3 & 15;
  int b    = t3 >> 4;
  int tloc = q >> 2, gi = q & 3;
  int tap  = tg*3 + tloc;
  int ci   = c0*32 + gi*8;
  union { uint4 v; unsigned short h[8]; } in, outv;
  in.v = *reinterpret_cast<const uint4*>(wpack + (tap*COUT + co)*CIN + ci);
  float dv = D[b*COUT + co];
  float4 s0 = *reinterpret_cast<const float4*>(S + b*CIN + ci);
  float4 s1 = *reinterpret_cast<const float4*>(S + b*CIN + ci + 4);
  float sv[8] = {s0.x, s0.y, s0.z, s0.w, s1.x, s1.y, s1.z, s1.w};
  #pragma unroll
  for (int j = 0; j < 8; ++j) outv.h[j] = f2bf(bf2f(in.h[j]) * sv[j] * dv);
  *reinterpret_cast<uint4*>(wmodK + g*8) = outv.v;
}

// Main conv. Sections = (ci-chunk of 32) x (tap-group of 3) = 48 barrier pairs,
// 48 MFMA per pair. A (6xuint4) and B-halo (32 fp32) register-prefetched one
// section ahead so global latency overlaps the MFMA body.
#define PK   104   // As K-stride pad: 208 B = 20-bank pattern, conflict-free b128
#define BPAD 40    // Bs ci-stride pad: 80 B = 20-bank pattern
__global__ __launch_bounds__(256, 3) void k_conv(const float* __restrict__ in,
                                                 const unsigned short* __restrict__ wmodK,
                                                 float* __restrict__ out) {
  const int b   = blockIdx.z;
  const int co0 = blockIdx.y * 128;
  const int pt  = blockIdx.x;
  const int h0  = pt * 2;

  const int tid  = threadIdx.x;
  const int lane = tid & 63;
  const int wave = tid >> 6;
  const int wm   = wave >> 1;
  const int wn   = wave & 1;
  const int l15  = lane & 15;
  const int quad = lane >> 4;

  __shared__ __align__(16) unsigned short As[128 * PK];       // 26.6 KB
  __shared__ __align__(16) unsigned short Bs[4 * 66 * BPAD];  // 21.1 KB

  f32x4 zero = {0.f, 0.f, 0.f, 0.f};
  f32x4 acc[4][4];
  #pragma unroll
  for (int i = 0; i < 4; ++i)
    #pragma unroll
    for (int j = 0; j < 4; ++j) acc[i][j] = zero;

  const float* inb = in + b * (CIN * HW);
  const unsigned short* wKb = wmodK + b * (16 * 3 * COUT * 96);

  // halo cols 0 and 65 (img w=-1,64) are always zero; write once
  if (tid < 32) {
    int row = tid >> 3, rem = tid & 7;
    int ch  = (rem >> 2) * 65;
    int ci8 = (rem & 3) * 8;
    uint4 z = {0u, 0u, 0u, 0u};
    *reinterpret_cast<uint4*>(&Bs[(row*66 + ch)*BPAD + ci8]) = z;
  }

  // A-staging slice: row = tid>>1 (co), h = tid&1 (half of 96)
  const int arow = tid >> 1;
  const int ah   = tid & 1;
  // B-staging: halo row srow (wave-uniform), image col scol
  const int scol = tid & 63;
  const int srow = tid >> 6;
  const int gI   = h0 - 1 + srow;
  const bool inr = (gI >= 0) && (gI < HDIM);

  // frag read offsets
  int a_row_off[4], b_base[4];
  #pragma unroll
  for (int mt = 0; mt < 4; ++mt) a_row_off[mt] = (wm*64 + mt*16 + l15) * PK + quad*8;
  #pragma unroll
  for (int nt = 0; nt < 4; ++nt) {
    int px = wn*64 + nt*16 + l15;
    int r = px >> 6, c = px & 63;
    b_base[nt] = (r*66 + c) * BPAD + quad*8;
  }

  uint4 aPf[6];
  float bPf[32];

  auto loadA = [&](int sec) {
    const unsigned short* p = wKb + sec*(COUT*96) + (co0 + arow)*96 + ah*48;
    #pragma unroll
    for (int i = 0; i < 6; ++i) aPf[i] = *reinterpret_cast<const uint4*>(p + i*8);
  };
  auto loadB = [&](int c0) {
    const float* src = inb + (c0*32)*HW + gI*HDIM + scol;
    #pragma unroll
    for (int j = 0; j < 32; ++j) bPf[j] = inr ? src[j*HW] : 0.f;
  };

  loadA(0);
  loadB(0);

  #pragma unroll 1
  for (int sec = 0; sec < 48; ++sec) {
    const int tg = sec % 3;
    // ---- write prefetched data to LDS ----
    {
      unsigned short* ap = &As[arow*PK + ah*48];
      #pragma unroll
      for (int i = 0; i < 6; ++i) *reinterpret_cast<uint4*>(ap + i*8) = aPf[i];
    }
    if (tg == 0) {
      unsigned short* bp = &Bs[(srow*66 + scol + 1)*BPAD];
      #pragma unroll
      for (int cg = 0; cg < 4; ++cg) {
        unsigned short h[8];
        #pragma unroll
        for (int j = 0; j < 8; ++j) h[j] = f2bf(bPf[cg*8 + j]);
        uint4 pk;
        pk.x = (unsigned)h[0] | ((unsigned)h[1] << 16);
        pk.y = (unsigned)h[2] | ((unsigned)h[3] << 16);
        pk.z = (unsigned)h[4] | ((unsigned)h[5] << 16);
        pk.w = (unsigned)h[6] | ((unsigned)h[7] << 16);
        *reinterpret_cast<uint4*>(bp + cg*8) = pk;
      }
    }
    __syncthreads();
    // ---- prefetch next section (hidden under MFMA body below) ----
    if (sec + 1 < 48) {
      loadA(sec + 1);
      if (tg == 2) loadB(sec/3 + 1);
    }
    // ---- compute: 3 k-steps (kw = ks), kh = tg ----
    #pragma unroll
    for (int ks = 0; ks < 3; ++ks) {
      const int toff = (tg*66 + ks) * BPAD;
      bf16x8 af[4], bfr[4];
      #pragma unroll
      for (int mt = 0; mt < 4; ++mt) {
        uint4 raw = *reinterpret_cast<const uint4*>(&As[a_row_off[mt] + ks*32]);
        af[mt] = __builtin_bit_cast(bf16x8, raw);
      }
      #pragma unroll
      for (int nt = 0; nt < 4; ++nt) {
        uint4 raw = *reinterpret_cast<const uint4*>(&Bs[b_base[nt] + toff]);
        bfr[nt] = __builtin_bit_cast(bf16x8, raw);
      }
      #pragma unroll
      for (int mt = 0; mt < 4; ++mt)
        #pragma unroll
        for (int nt = 0; nt < 4; ++nt)
          acc[mt][nt] = __builtin_amdgcn_mfma_f32_16x16x32_bf16(af[mt], bfr[nt], acc[mt][nt], 0, 0, 0);
    }
    __syncthreads();
  }

  // epilogue: C/D layout col=lane&15 (pixel), row=quad*4+reg (co)
  #pragma unroll
  for (int mt = 0; mt < 4; ++mt) {
    int co = co0 + wm*64 + mt*16 + quad*4;
    #pragma unroll
    for (int nt = 0; nt < 4; ++nt) {
      int px = pt*128 + wn*64 + nt*16 + l15;
      float* op = out + (b*COUT + co)*HW + px;
      #pragma unroll
      for (int r = 0; r < 4; ++r) op[r*HW] = acc[mt][nt][r];
    }
  }
}

extern "C" void kernel_launch(void* const* d_in, const int* in_sizes, int n_in,
                              void* d_out, int out_size, void* d_ws, size_t ws_size,
                              hipStream_t stream) {
  const float* input  = (const float*)d_in[0];
  const float* style  = (const float*)d_in[1];
  const float* weight = (const float*)d_in[2];
  const float* mod_w  = (const float*)d_in[3];
  const float* mod_b  = (const float*)d_in[4];
  float* out = (float*)d_out;

  char* ws = (char*)d_ws;
  float* S = (float*)ws;                                   //    32 KB
  float* D = (float*)(ws + 32768);                         //    32 KB
  float* wsq = (float*)(ws + 65536);                       //     1 MB
  unsigned short* wpack = (unsigned short*)(ws + 65536 + 1048576);           // 9.4 MB
  unsigned short* wmodK = (unsigned short*)(ws + 65536 + 1048576 + 9437184); // 75.5 MB

  k_style<<<dim3(BATCH, 4), 128, 0, stream>>>(style, mod_w, mod_b, S);
  k_wsq_pack<<<COUT, 256, 0, stream>>>(weight, wsq, wpack);
  k_demod<<<(BATCH*COUT)/4, 256, 0, stream>>>(S, wsq, D);
  k_wmod<<<(BATCH*16*3*COUT*12)/256, 256, 0, stream>>>(wpack, S, D, wmodK);

  dim3 grid(HW/128, COUT/128, BATCH);
  k_conv<<<grid, 256, 0, stream>>>(input, wmodK, out);
}

// Round 3
// 1005.017 us; speedup vs baseline: 1.0296x; 1.0296x over previous
//
#include <hip/hip_runtime.h>

#define BATCH 16
#define CIN   512
#define COUT  512
#define HDIM  64
#define HW    4096
#define STY   512
#define NTAP  9
// 1/sqrt(512*9)
#define SCALE 0.014731391274719739f

typedef __bf16 bf16x8 __attribute__((ext_vector_type(8)));
typedef float  f32x4  __attribute__((ext_vector_type(4)));

static __device__ __forceinline__ unsigned short f2bf(float f) {
  union { float f; unsigned u; } v; v.f = f;
  unsigned u = v.u;
  u += 0x7fffu + ((u >> 16) & 1u);   // RNE; inputs finite
  return (unsigned short)(u >> 16);
}

// S[b][ci] = SCALE * (sum_j style[b][j]*mod_w[ci][j] + mod_b[ci])
__global__ void k_style(const float* __restrict__ style, const float* __restrict__ mod_w,
                        const float* __restrict__ mod_b, float* __restrict__ S) {
  __shared__ __align__(16) float sty[STY];
  int b = blockIdx.x;
  for (int j = threadIdx.x; j < STY; j += 128) sty[j] = style[b*STY + j];
  __syncthreads();
  int ci = blockIdx.y * 128 + threadIdx.x;
  const float4* wr = reinterpret_cast<const float4*>(mod_w + ci*STY);
  const float4* sr = reinterpret_cast<const float4*>(sty);
  float acc = 0.f;
  #pragma unroll 4
  for (int j = 0; j < STY/4; ++j) {
    float4 w = wr[j], s = sr[j];
    acc += w.x*s.x + w.y*s.y + w.z*s.z + w.w*s.w;
  }
  S[b*CIN + ci] = SCALE * (acc + mod_b[ci]);
}

// wsq[co][ci] = sum_tap w^2 (fp32, for demod) ;
// wpackK[c0][tg][co][96] = bf16 weight in GEMM-K order:
//   k96 = tloc*32 + cil -> tap = tg*3 + tloc, ci = c0*32 + cil
__global__ void k_prep(const float* __restrict__ weight, float* __restrict__ wsq,
                       unsigned short* __restrict__ wpackK) {
  __shared__ __align__(16) float w[CIN*NTAP];
  int co = blockIdx.x;
  for (int i = threadIdx.x; i < CIN*NTAP; i += 256)
    w[i] = weight[co*(CIN*NTAP) + i];
  __syncthreads();
  for (int ci = threadIdx.x; ci < CIN; ci += 256) {
    int c0 = ci >> 5, cil = ci & 31;
    float ssq = 0.f;
    #pragma unroll
    for (int t = 0; t < NTAP; ++t) {
      float v = w[ci*NTAP + t];
      ssq += v * v;
      int tg = t / 3, tloc = t - 3*tg;
      wpackK[((c0*3 + tg)*COUT + co)*96 + tloc*32 + cil] = f2bf(v);
    }
    wsq[co*CIN + ci] = ssq;
  }
}

// D[b][co] = rsqrt(sum_ci S^2 * wsq + eps); one wave per (b,co)
__global__ void k_demod(const float* __restrict__ S, const float* __restrict__ wsq,
                        float* __restrict__ D) {
  int wid  = blockIdx.x * 4 + (threadIdx.x >> 6);
  int lane = threadIdx.x & 63;
  int b  = wid >> 9;
  int co = wid & 511;
  float sum = 0.f;
  #pragma unroll
  for (int i = 0; i < CIN/64; ++i) {
    int ci = lane + i*64;
    float s = S[b*CIN + ci];
    sum += s * s * wsq[co*CIN + ci];
  }
  #pragma unroll
  for (int off = 32; off > 0; off >>= 1) sum += __shfl_down(sum, off);
  if (lane == 0) D[b*COUT + co] = rsqrtf(sum + 1e-8f);
}

// Main conv: D[co] * conv(x*S[ci], bf16(weight)).
// 48 sections of K=96 (ci-chunk 32 x tap-group 3), 48 MFMA per barrier pair.
// A staged direct (no prefetch arrays - round 2's spill), 6x16B/thread from
// L2-resident wpackK. B halo staged once per ci-chunk with S fused.
#define PK   104   // As K-stride pad: 208 B = 20-bank stride, <=2-way
#define BPAD 40    // Bs ci-stride pad: 80 B = 20-bank stride
__global__ __launch_bounds__(256, 3) void k_conv(const float* __restrict__ in,
                                                 const unsigned short* __restrict__ wpackK,
                                                 const float* __restrict__ S,
                                                 const float* __restrict__ D,
                                                 float* __restrict__ out) {
  const int b   = blockIdx.z;
  const int co0 = blockIdx.y * 128;
  const int pt  = blockIdx.x;
  const int h0  = pt * 2;

  const int tid  = threadIdx.x;
  const int lane = tid & 63;
  const int wave = tid >> 6;
  const int wm   = wave >> 1;
  const int wn   = wave & 1;
  const int l15  = lane & 15;
  const int quad = lane >> 4;

  __shared__ __align__(16) unsigned short As[128 * PK];       // 26.6 KB
  __shared__ __align__(16) unsigned short Bs[4 * 66 * BPAD];  // 21.1 KB
  __shared__ __align__(16) float Ssh[CIN];                    //  2 KB
  __shared__ __align__(16) float Dsh[128];                    // 0.5 KB

  f32x4 zero = {0.f, 0.f, 0.f, 0.f};
  f32x4 acc[4][4];
  #pragma unroll
  for (int i = 0; i < 4; ++i)
    #pragma unroll
    for (int j = 0; j < 4; ++j) acc[i][j] = zero;

  const float* inb = in + b * (CIN * HW);

  // stage S (per-ci scale) and D (per-co demod) for this block
  {
    float2 s2 = *reinterpret_cast<const float2*>(S + b*CIN + tid*2);
    *reinterpret_cast<float2*>(&Ssh[tid*2]) = s2;
    if (tid < 128) Dsh[tid] = D[b*COUT + co0 + tid];
  }
  // halo cols 0 and 65 (img w=-1,64) are always zero; write once
  if (tid < 32) {
    int row = tid >> 3, rem = tid & 7;
    int ch  = (rem >> 2) * 65;
    int ci8 = (rem & 3) * 8;
    uint4 z = {0u, 0u, 0u, 0u};
    *reinterpret_cast<uint4*>(&Bs[(row*66 + ch)*BPAD + ci8]) = z;
  }
  __syncthreads();   // Ssh ready for first B staging

  // A-staging slice: row = tid>>1 (co), half = tid&1 (48 of 96 K)
  const int arow = tid >> 1;
  const int ah   = tid & 1;
  // B-staging: halo row (wave-uniform), image col
  const int scol = tid & 63;
  const int srow = tid >> 6;
  const int gI   = h0 - 1 + srow;
  const bool inr = (gI >= 0) && (gI < HDIM);

  // frag read offsets (elements)
  int a_row_off[4], b_base[4];
  #pragma unroll
  for (int mt = 0; mt < 4; ++mt) a_row_off[mt] = (wm*64 + mt*16 + l15) * PK + quad*8;
  #pragma unroll
  for (int nt = 0; nt < 4; ++nt) {
    int px = wn*64 + nt*16 + l15;
    int r = px >> 6, c = px & 63;
    b_base[nt] = (r*66 + c) * BPAD + quad*8;
  }

  const unsigned short* asrc = wpackK + (co0 + arow)*96 + ah*48;

  #pragma unroll 1
  for (int c0 = 0; c0 < 16; ++c0) {
    #pragma unroll 1
    for (int tg = 0; tg < 3; ++tg) {
      // ---- stage A: 6x16B contiguous per thread (L2-resident source) ----
      {
        unsigned short* ap = &As[arow*PK + ah*48];
        #pragma unroll
        for (int i = 0; i < 6; ++i) {
          uint4 v = *reinterpret_cast<const uint4*>(asrc + i*8);
          *reinterpret_cast<uint4*>(ap + i*8) = v;
        }
        asrc += COUT*96;
      }
      // ---- stage B halo once per ci-chunk, with S fused ----
      if (tg == 0) {
        const int ci0 = c0 * 32;
        const float* src = inb + ci0*HW + gI*HDIM + scol;
        unsigned short* bp = &Bs[(srow*66 + scol + 1)*BPAD];
        #pragma unroll
        for (int cg = 0; cg < 4; ++cg) {
          unsigned short h[8];
          #pragma unroll
          for (int j = 0; j < 8; ++j) {
            float v = inr ? src[(cg*8 + j)*HW] * Ssh[ci0 + cg*8 + j] : 0.f;
            h[j] = f2bf(v);
          }
          uint4 pk;
          pk.x = (unsigned)h[0] | ((unsigned)h[1] << 16);
          pk.y = (unsigned)h[2] | ((unsigned)h[3] << 16);
          pk.z = (unsigned)h[4] | ((unsigned)h[5] << 16);
          pk.w = (unsigned)h[6] | ((unsigned)h[7] << 16);
          *reinterpret_cast<uint4*>(bp + cg*8) = pk;
        }
      }
      __syncthreads();
      // ---- compute: 3 k-steps (kw = ks), kh = tg ----
      #pragma unroll
      for (int ks = 0; ks < 3; ++ks) {
        const int toff = (tg*66 + ks) * BPAD;
        bf16x8 af[4], bfr[4];
        #pragma unroll
        for (int mt = 0; mt < 4; ++mt) {
          uint4 raw = *reinterpret_cast<const uint4*>(&As[a_row_off[mt] + ks*32]);
          af[mt] = __builtin_bit_cast(bf16x8, raw);
        }
        #pragma unroll
        for (int nt = 0; nt < 4; ++nt) {
          uint4 raw = *reinterpret_cast<const uint4*>(&Bs[b_base[nt] + toff]);
          bfr[nt] = __builtin_bit_cast(bf16x8, raw);
        }
        #pragma unroll
        for (int mt = 0; mt < 4; ++mt)
          #pragma unroll
          for (int nt = 0; nt < 4; ++nt)
            acc[mt][nt] = __builtin_amdgcn_mfma_f32_16x16x32_bf16(af[mt], bfr[nt], acc[mt][nt], 0, 0, 0);
      }
      __syncthreads();
    }
  }

  // epilogue: C/D layout col=lane&15 (pixel), row=quad*4+reg (co); fuse demod D
  #pragma unroll
  for (int mt = 0; mt < 4; ++mt) {
    int coL = wm*64 + mt*16 + quad*4;
    #pragma unroll
    for (int nt = 0; nt < 4; ++nt) {
      int px = pt*128 + wn*64 + nt*16 + l15;
      float* op = out + (b*COUT + co0 + coL)*HW + px;
      #pragma unroll
      for (int r = 0; r < 4; ++r) op[r*HW] = acc[mt][nt][r] * Dsh[coL + r];
    }
  }
}

extern "C" void kernel_launch(void* const* d_in, const int* in_sizes, int n_in,
                              void* d_out, int out_size, void* d_ws, size_t ws_size,
                              hipStream_t stream) {
  const float* input  = (const float*)d_in[0];
  const float* style  = (const float*)d_in[1];
  const float* weight = (const float*)d_in[2];
  const float* mod_w  = (const float*)d_in[3];
  const float* mod_b  = (const float*)d_in[4];
  float* out = (float*)d_out;

  char* ws = (char*)d_ws;
  float* S   = (float*)ws;                          //   32 KB
  float* D   = (float*)(ws + 32768);                //   32 KB
  float* wsq = (float*)(ws + 65536);                //    1 MB
  unsigned short* wpackK = (unsigned short*)(ws + 65536 + 1048576);  // 4.72 MB

  k_style<<<dim3(BATCH, 4), 128, 0, stream>>>(style, mod_w, mod_b, S);
  k_prep<<<COUT, 256, 0, stream>>>(weight, wsq, wpackK);
  k_demod<<<(BATCH*COUT)/4, 256, 0, stream>>>(S, wsq, D);

  dim3 grid(HW/128, COUT/128, BATCH);
  k_conv<<<grid, 256, 0, stream>>>(input, wpackK, S, D, out);
}